// Round 11
// baseline (572.611 us; speedup 1.0000x reference)
//
#include <hip/hip_runtime.h>
#include <stdint.h>

typedef float f32x4 __attribute__((ext_vector_type(4)));

// Phase 1 (persistent-wave, 2-deep NT prefetch pipeline):
//   8192 waves, 8 words each. Each steady-state iteration issues the NEXT
//   word's 8 NT loads before computing the CURRENT word's ballots, so the
//   compiler waits with vmcnt(8) (current word only) and every wave keeps
//   8-16 KiB outstanding CONTINUOUSLY — no load-drain-retire duty cycle
//   (the suspected reason phase 1 ran at ~4.6 TB/s vs the 6.3 TB/s ceiling).
//   Loop body stores only 4 B/word to ws -> DRAM sees a pure NT read stream.
//   Last iteration is PEELED so the steady-state body is branchless.
// Phase 2: 4 B wave-uniform read (L2-hot) -> 4 KiB one-hot cached stores;
//   pure write stream, same pattern as the 6.55 TB/s fill reference.

__device__ __forceinline__ uint32_t idx_of(const f32x4 v) {
    const uint64_t m0 = __ballot(v.x > 0.5f);
    const uint64_t m1 = __ballot(v.y > 0.5f);
    const uint64_t m2 = __ballot(v.z > 0.5f);
    const uint64_t m3 = __ballot(v.w > 0.5f);
    const uint64_t m  = m0 | m1 | m2 | m3;
    const uint32_t hl = (uint32_t)__ffsll((unsigned long long)m) - 1u;
    const uint32_t c  = (m1 ? 1u : 0u) | (m2 ? 2u : 0u) | (m3 ? 3u : 0u);
    return hl * 4u + c;
}

__global__ __launch_bounds__(256) void vm_phase1(
    const float* __restrict__ a_bytes,
    const float* __restrict__ b_bytes,
    uint32_t* __restrict__ ws,
    int n_words)
{
    const int lane   = threadIdx.x & 63;
    const int wv     = blockIdx.x * 4 + (threadIdx.x >> 6);
    const int nwaves = gridDim.x * 4;
    const long lofs  = lane * 4;

    int w = wv;
    if (w >= n_words) return;

    // ---- prologue: load word w ----
    const float* pa = a_bytes + (long)w * 1024 + lofs;
    const float* pb = b_bytes + (long)w * 1024 + lofs;
    f32x4 A0 = __builtin_nontemporal_load((const f32x4*)(pa));
    f32x4 A1 = __builtin_nontemporal_load((const f32x4*)(pa + 256));
    f32x4 A2 = __builtin_nontemporal_load((const f32x4*)(pa + 512));
    f32x4 A3 = __builtin_nontemporal_load((const f32x4*)(pa + 768));
    f32x4 B0 = __builtin_nontemporal_load((const f32x4*)(pb));
    f32x4 B1 = __builtin_nontemporal_load((const f32x4*)(pb + 256));
    f32x4 B2 = __builtin_nontemporal_load((const f32x4*)(pb + 512));
    f32x4 B3 = __builtin_nontemporal_load((const f32x4*)(pb + 768));

    // ---- steady state: branchless body, prefetch next then compute current ----
    while (w + nwaves < n_words) {
        const int wn = w + nwaves;
        const float* qa = a_bytes + (long)wn * 1024 + lofs;
        const float* qb = b_bytes + (long)wn * 1024 + lofs;
        const f32x4 An0 = __builtin_nontemporal_load((const f32x4*)(qa));
        const f32x4 An1 = __builtin_nontemporal_load((const f32x4*)(qa + 256));
        const f32x4 An2 = __builtin_nontemporal_load((const f32x4*)(qa + 512));
        const f32x4 An3 = __builtin_nontemporal_load((const f32x4*)(qa + 768));
        const f32x4 Bn0 = __builtin_nontemporal_load((const f32x4*)(qb));
        const f32x4 Bn1 = __builtin_nontemporal_load((const f32x4*)(qb + 256));
        const f32x4 Bn2 = __builtin_nontemporal_load((const f32x4*)(qb + 512));
        const f32x4 Bn3 = __builtin_nontemporal_load((const f32x4*)(qb + 768));

        const uint32_t aw = idx_of(A0) | (idx_of(A1) << 8) |
                            (idx_of(A2) << 16) | (idx_of(A3) << 24);
        const uint32_t bw = idx_of(B0) | (idx_of(B1) << 8) |
                            (idx_of(B2) << 16) | (idx_of(B3) << 24);
        const uint32_t s = aw + bw;   // ripple-carry add; carry of byte 3 dropped
        const uint32_t o = s ^ aw;    // chained per-byte XOR with operand a
        if (lane == 0) ws[w] = o;

        A0 = An0; A1 = An1; A2 = An2; A3 = An3;
        B0 = Bn0; B1 = Bn1; B2 = Bn2; B3 = Bn3;
        w = wn;
    }

    // ---- epilogue: last word ----
    {
        const uint32_t aw = idx_of(A0) | (idx_of(A1) << 8) |
                            (idx_of(A2) << 16) | (idx_of(A3) << 24);
        const uint32_t bw = idx_of(B0) | (idx_of(B1) << 8) |
                            (idx_of(B2) << 16) | (idx_of(B3) << 24);
        const uint32_t s = aw + bw;
        const uint32_t o = s ^ aw;
        if (lane == 0) ws[w] = o;
    }
}

__global__ __launch_bounds__(256) void vm_phase2(
    const uint32_t* __restrict__ ws,
    float* __restrict__ out,
    int n_words)
{
    const int lane = threadIdx.x & 63;
    const int w    = blockIdx.x * 4 + (threadIdx.x >> 6);
    if (w >= n_words) return;

    const uint32_t o = ws[w];            // wave-uniform -> scalar load, L2-hot
    float* po = out + (long)w * 1024 + lane * 4;
    const int j = lane * 4;
#pragma unroll
    for (int k = 0; k < 4; ++k) {
        const int oi = (int)((o >> (8 * k)) & 255u);
        f32x4 ov;
        ov.x = (j     == oi) ? 1.0f : 0.0f;
        ov.y = (j + 1 == oi) ? 1.0f : 0.0f;
        ov.z = (j + 2 == oi) ? 1.0f : 0.0f;
        ov.w = (j + 3 == oi) ? 1.0f : 0.0f;
        *(f32x4*)(po + k * 256) = ov;    // cached store, fill-kernel pattern
    }
}

// Fallback: fused all-NT single pass (R5) if ws is unavailable/too small.
__global__ __launch_bounds__(256) void vm_fused(
    const float* __restrict__ a_bytes,
    const float* __restrict__ b_bytes,
    float* __restrict__ out,
    int n_words)
{
    const int lane = threadIdx.x & 63;
    const int w    = blockIdx.x * 4 + (threadIdx.x >> 6);
    if (w >= n_words) return;

    const long base = (long)w * 1024 + lane * 4;
    const float* pa = a_bytes + base;
    const float* pb = b_bytes + base;

    const f32x4 a0 = __builtin_nontemporal_load((const f32x4*)(pa));
    const f32x4 a1 = __builtin_nontemporal_load((const f32x4*)(pa + 256));
    const f32x4 a2 = __builtin_nontemporal_load((const f32x4*)(pa + 512));
    const f32x4 a3 = __builtin_nontemporal_load((const f32x4*)(pa + 768));
    const f32x4 b0 = __builtin_nontemporal_load((const f32x4*)(pb));
    const f32x4 b1 = __builtin_nontemporal_load((const f32x4*)(pb + 256));
    const f32x4 b2 = __builtin_nontemporal_load((const f32x4*)(pb + 512));
    const f32x4 b3 = __builtin_nontemporal_load((const f32x4*)(pb + 768));

    const uint32_t aw = idx_of(a0) | (idx_of(a1) << 8) |
                        (idx_of(a2) << 16) | (idx_of(a3) << 24);
    const uint32_t bw = idx_of(b0) | (idx_of(b1) << 8) |
                        (idx_of(b2) << 16) | (idx_of(b3) << 24);
    const uint32_t s = aw + bw;
    const uint32_t o = s ^ aw;

    float* po = out + base;
    const int j = lane * 4;
#pragma unroll
    for (int k = 0; k < 4; ++k) {
        const int oi = (int)((o >> (8 * k)) & 255u);
        f32x4 ov;
        ov.x = (j     == oi) ? 1.0f : 0.0f;
        ov.y = (j + 1 == oi) ? 1.0f : 0.0f;
        ov.z = (j + 2 == oi) ? 1.0f : 0.0f;
        ov.w = (j + 3 == oi) ? 1.0f : 0.0f;
        __builtin_nontemporal_store(ov, (f32x4*)(po + k * 256));
    }
}

extern "C" void kernel_launch(void* const* d_in, const int* in_sizes, int n_in,
                              void* d_out, int out_size, void* d_ws, size_t ws_size,
                              hipStream_t stream)
{
    const float* a_bytes = (const float*)d_in[0];  // [B,4,256]
    const float* b_bytes = (const float*)d_in[1];  // [B,4,256]
    float* out = (float*)d_out;                    // [B,4,256]
    const int n_words = in_sizes[0] / 1024;        // B
    const int blocks  = (n_words + 3) / 4;         // 4 waves/block, 1 word/wave

    if (d_ws != nullptr && ws_size >= (size_t)n_words * 4) {
        uint32_t* ws = (uint32_t*)d_ws;
        // persistent waves: 2048 blocks = 8192 waves -> 8 words/wave at B=65536
        int p1_blocks = (blocks < 2048) ? blocks : 2048;
        if (p1_blocks < 1) p1_blocks = 1;
        vm_phase1<<<p1_blocks, 256, 0, stream>>>(a_bytes, b_bytes, ws, n_words);
        vm_phase2<<<blocks, 256, 0, stream>>>(ws, out, n_words);
    } else {
        vm_fused<<<blocks, 256, 0, stream>>>(a_bytes, b_bytes, out, n_words);
    }
}

// Round 12
// 548.033 us; speedup vs baseline: 1.0448x; 1.0448x over previous
//
#include <hip/hip_runtime.h>
#include <stdint.h>

typedef float f32x4 __attribute__((ext_vector_type(4)));
typedef float f32x2 __attribute__((ext_vector_type(2)));

// Phase 1 (half-read skip): each 256-float chunk is ONE-HOT, so read only the
// first 512 B (floats 0..127, lane l holds floats 2l,2l+1 via NT float2).
// With p=1/2 the 1.0 is found and the second 512 B is NEVER read (a real
// 4-DRAM-line skip). Miss branches are wave-uniform (ballot), all second-half
// loads are issued before any resolve (single extra round trip, hidden by
// other waves — R9/R11 proved we're rate-capped, not latency-capped).
// Expected demand: 6 KiB/word vs 8 KiB -> 537 MB -> ~404 MB.
// Phase 2: 4 B wave-uniform read (L2-hot) -> 4 KiB one-hot cached stores;
// pure write stream, same pattern as the 6.55 TB/s fill reference.

__global__ __launch_bounds__(256) void vm_phase1(
    const float* __restrict__ a_bytes,
    const float* __restrict__ b_bytes,
    uint32_t* __restrict__ ws,
    int n_words)
{
    const int lane = threadIdx.x & 63;
    const int w    = blockIdx.x * 4 + (threadIdx.x >> 6);
    if (w >= n_words) return;

    const float* pa = a_bytes + (long)w * 1024;
    const float* pb = b_bytes + (long)w * 1024;

    // chunk c: c<4 -> a chunk c ; c>=4 -> b chunk c-4
    f32x2 v[8];
#pragma unroll
    for (int c = 0; c < 8; ++c) {
        const float* p = (c < 4 ? pa + c * 256 : pb + (c - 4) * 256) + lane * 2;
        v[c] = __builtin_nontemporal_load((const f32x2*)p);
    }

    uint32_t idx[8];
    bool found[8];
#pragma unroll
    for (int c = 0; c < 8; ++c) {
        const uint64_t m0 = __ballot(v[c].x > 0.5f);
        const uint64_t m1 = __ballot(v[c].y > 0.5f);
        const uint64_t m  = m0 | m1;
        found[c] = (m != 0);                       // wave-uniform
        idx[c] = 2u * ((uint32_t)__ffsll((unsigned long long)m) - 1u) +
                 (m1 ? 1u : 0u);
    }

    // Issue ALL needed second halves first (no waits inside this loop) ...
#pragma unroll
    for (int c = 0; c < 8; ++c) {
        if (!found[c]) {
            const float* p = (c < 4 ? pa + c * 256 : pb + (c - 4) * 256) + 128 + lane * 2;
            v[c] = __builtin_nontemporal_load((const f32x2*)p);
        }
    }
    // ... then resolve them (waits overlap across chunks).
#pragma unroll
    for (int c = 0; c < 8; ++c) {
        if (!found[c]) {
            const uint64_t m0 = __ballot(v[c].x > 0.5f);
            const uint64_t m1 = __ballot(v[c].y > 0.5f);
            const uint64_t m  = m0 | m1;
            idx[c] = 128u + 2u * ((uint32_t)__ffsll((unsigned long long)m) - 1u) +
                     (m1 ? 1u : 0u);
        }
    }

    const uint32_t aw = idx[0] | (idx[1] << 8) | (idx[2] << 16) | (idx[3] << 24);
    const uint32_t bw = idx[4] | (idx[5] << 8) | (idx[6] << 16) | (idx[7] << 24);
    const uint32_t s = aw + bw;   // ripple-carry add; carry out of byte 3 dropped
    const uint32_t o = s ^ aw;    // chained per-byte XOR with operand a
    if (lane == 0) ws[w] = o;
}

__global__ __launch_bounds__(256) void vm_phase2(
    const uint32_t* __restrict__ ws,
    float* __restrict__ out,
    int n_words)
{
    const int lane = threadIdx.x & 63;
    const int w    = blockIdx.x * 4 + (threadIdx.x >> 6);
    if (w >= n_words) return;

    const uint32_t o = ws[w];            // wave-uniform -> scalar load, L2-hot
    float* po = out + (long)w * 1024 + lane * 4;
    const int j = lane * 4;
#pragma unroll
    for (int k = 0; k < 4; ++k) {
        const int oi = (int)((o >> (8 * k)) & 255u);
        f32x4 ov;
        ov.x = (j     == oi) ? 1.0f : 0.0f;
        ov.y = (j + 1 == oi) ? 1.0f : 0.0f;
        ov.z = (j + 2 == oi) ? 1.0f : 0.0f;
        ov.w = (j + 3 == oi) ? 1.0f : 0.0f;
        *(f32x4*)(po + k * 256) = ov;    // cached store, fill-kernel pattern
    }
}

// Fallback: fused all-NT single pass (R5) if ws is unavailable/too small.
__device__ __forceinline__ uint32_t idx_of16(const f32x4 v) {
    const uint64_t m0 = __ballot(v.x > 0.5f);
    const uint64_t m1 = __ballot(v.y > 0.5f);
    const uint64_t m2 = __ballot(v.z > 0.5f);
    const uint64_t m3 = __ballot(v.w > 0.5f);
    const uint64_t m  = m0 | m1 | m2 | m3;
    const uint32_t hl = (uint32_t)__ffsll((unsigned long long)m) - 1u;
    const uint32_t c  = (m1 ? 1u : 0u) | (m2 ? 2u : 0u) | (m3 ? 3u : 0u);
    return hl * 4u + c;
}

__global__ __launch_bounds__(256) void vm_fused(
    const float* __restrict__ a_bytes,
    const float* __restrict__ b_bytes,
    float* __restrict__ out,
    int n_words)
{
    const int lane = threadIdx.x & 63;
    const int w    = blockIdx.x * 4 + (threadIdx.x >> 6);
    if (w >= n_words) return;

    const long base = (long)w * 1024 + lane * 4;
    const float* pa = a_bytes + base;
    const float* pb = b_bytes + base;

    const f32x4 a0 = __builtin_nontemporal_load((const f32x4*)(pa));
    const f32x4 a1 = __builtin_nontemporal_load((const f32x4*)(pa + 256));
    const f32x4 a2 = __builtin_nontemporal_load((const f32x4*)(pa + 512));
    const f32x4 a3 = __builtin_nontemporal_load((const f32x4*)(pa + 768));
    const f32x4 b0 = __builtin_nontemporal_load((const f32x4*)(pb));
    const f32x4 b1 = __builtin_nontemporal_load((const f32x4*)(pb + 256));
    const f32x4 b2 = __builtin_nontemporal_load((const f32x4*)(pb + 512));
    const f32x4 b3 = __builtin_nontemporal_load((const f32x4*)(pb + 768));

    const uint32_t aw = idx_of16(a0) | (idx_of16(a1) << 8) |
                        (idx_of16(a2) << 16) | (idx_of16(a3) << 24);
    const uint32_t bw = idx_of16(b0) | (idx_of16(b1) << 8) |
                        (idx_of16(b2) << 16) | (idx_of16(b3) << 24);
    const uint32_t s = aw + bw;
    const uint32_t o = s ^ aw;

    float* po = out + base;
    const int j = lane * 4;
#pragma unroll
    for (int k = 0; k < 4; ++k) {
        const int oi = (int)((o >> (8 * k)) & 255u);
        f32x4 ov;
        ov.x = (j     == oi) ? 1.0f : 0.0f;
        ov.y = (j + 1 == oi) ? 1.0f : 0.0f;
        ov.z = (j + 2 == oi) ? 1.0f : 0.0f;
        ov.w = (j + 3 == oi) ? 1.0f : 0.0f;
        __builtin_nontemporal_store(ov, (f32x4*)(po + k * 256));
    }
}

extern "C" void kernel_launch(void* const* d_in, const int* in_sizes, int n_in,
                              void* d_out, int out_size, void* d_ws, size_t ws_size,
                              hipStream_t stream)
{
    const float* a_bytes = (const float*)d_in[0];  // [B,4,256]
    const float* b_bytes = (const float*)d_in[1];  // [B,4,256]
    float* out = (float*)d_out;                    // [B,4,256]
    const int n_words = in_sizes[0] / 1024;        // B
    const int blocks  = (n_words + 3) / 4;         // 4 waves/block, 1 word/wave

    if (d_ws != nullptr && ws_size >= (size_t)n_words * 4) {
        uint32_t* ws = (uint32_t*)d_ws;
        vm_phase1<<<blocks, 256, 0, stream>>>(a_bytes, b_bytes, ws, n_words);
        vm_phase2<<<blocks, 256, 0, stream>>>(ws, out, n_words);
    } else {
        vm_fused<<<blocks, 256, 0, stream>>>(a_bytes, b_bytes, out, n_words);
    }
}